// Round 1
// baseline (7261.661 us; speedup 1.0000x reference)
//
#include <hip/hip_runtime.h>
#include <cmath>

// 11-layer stacked LSTM, S=512, B=256, H=106 (gate dim 424).
// Parallelization: one block per batch row (grid=256 -> 1 block/CU),
// weights register-resident per thread (thread j owns gate row j),
// inputs [x_t | h_t] broadcast from LDS, fused input+recurrent GEMM,
// 2 barriers per timestep, c kept in registers of threads j<106.

namespace {
constexpr int H    = 106;
constexpr int G4   = 424;   // 4*H
constexpr int SEQ  = 512;
constexpr int BB   = 256;
constexpr int HPAD = 108;   // H rounded up to multiple of 4

__device__ __forceinline__ float fast_sigmoid(float x) {
    return 1.0f / (1.0f + __expf(-x));
}
__device__ __forceinline__ float fast_tanh(float x) {
    // 1 - 2/(e^{2x}+1): stable for +/- inf
    float t = __expf(2.0f * x);
    return 1.0f - 2.0f / (t + 1.0f);
}

template <int K_IN>
__global__ __launch_bounds__(448, 2)
void lstm_layer(const float* __restrict__ x,    // (S, B, K_IN)
                float* __restrict__ y,          // (S, B, H)
                const float* __restrict__ Wih,  // (4H, K_IN)
                const float* __restrict__ Whh,  // (4H, H)
                const float* __restrict__ bih,  // (4H)
                const float* __restrict__ bhh)  // (4H)
{
    constexpr int KPAD = (K_IN + 3) & ~3;

    const int b = blockIdx.x;    // batch row
    const int j = threadIdx.x;   // gate row (j < 424 active in GEMM)

    __shared__ __align__(16) float sx[112];   // x_t   (padded, pads = 0)
    __shared__ __align__(16) float sh[112];   // h_t   (padded, pads = 0)
    __shared__ float gates[G4];

    // ---- load this thread's weight rows into registers (one-time) ----
    float wih[KPAD];
    float whh[HPAD];
    float bias = 0.0f;
    if (j < G4) {
        const float* wr = Wih + (size_t)j * K_IN;
        #pragma unroll
        for (int k = 0; k < K_IN; ++k) wih[k] = wr[k];
        #pragma unroll
        for (int k = K_IN; k < KPAD; ++k) wih[k] = 0.0f;
        const float* hr = Whh + (size_t)j * H;
        #pragma unroll
        for (int k = 0; k < H; ++k) whh[k] = hr[k];
        #pragma unroll
        for (int k = H; k < HPAD; ++k) whh[k] = 0.0f;
        bias = bih[j] + bhh[j];
    }

    // ---- init state ----
    if (j < 112) { sh[j] = 0.0f; sx[j] = 0.0f; }
    if (j < K_IN) sx[j] = x[(size_t)b * K_IN + j];   // x_0
    float c = 0.0f;
    const int gate_id = j / H;           // 0:i 1:f 2:g 3:o
    const size_t xstride = (size_t)BB * K_IN;
    const float* xpre_ptr = x + (size_t)BB * K_IN + (size_t)b * K_IN + (j - 128);
    float* yptr = y + (size_t)b * H + j;
    __syncthreads();

    for (int s = 0; s < SEQ; ++s) {
        // prefetch x_{s+1} into registers (overlaps with the dot below)
        const bool pre = (s + 1 < SEQ) && (j >= 128) && (j < 128 + K_IN);
        float xpre = 0.0f;
        if (pre) xpre = xpre_ptr[(size_t)s * xstride];

        // ---- phase A: g = bias + Wih.x_t + Whh.h_t, activation ----
        if (j < G4) {
            float a0 = 0.0f, a1 = 0.0f, a2 = 0.0f, a3 = 0.0f;
            #pragma unroll
            for (int k4 = 0; k4 < KPAD / 4; ++k4) {
                float4 v = *reinterpret_cast<const float4*>(&sx[4 * k4]);
                a0 = fmaf(wih[4 * k4 + 0], v.x, a0);
                a1 = fmaf(wih[4 * k4 + 1], v.y, a1);
                a2 = fmaf(wih[4 * k4 + 2], v.z, a2);
                a3 = fmaf(wih[4 * k4 + 3], v.w, a3);
            }
            #pragma unroll
            for (int k4 = 0; k4 < HPAD / 4; ++k4) {
                float4 v = *reinterpret_cast<const float4*>(&sh[4 * k4]);
                a0 = fmaf(whh[4 * k4 + 0], v.x, a0);
                a1 = fmaf(whh[4 * k4 + 1], v.y, a1);
                a2 = fmaf(whh[4 * k4 + 2], v.z, a2);
                a3 = fmaf(whh[4 * k4 + 3], v.w, a3);
            }
            float g = bias + ((a0 + a1) + (a2 + a3));
            gates[j] = (gate_id == 2) ? fast_tanh(g) : fast_sigmoid(g);
        }
        __syncthreads();

        // ---- phase B: elementwise state update + h broadcast + output ----
        if (j < H) {
            float gi = gates[j];
            float gf = gates[H + j];
            float gg = gates[2 * H + j];
            float go = gates[3 * H + j];
            c = fmaf(gf, c, gi * gg);
            float h = go * fast_tanh(c);
            sh[j] = h;
            yptr[(size_t)s * BB * H] = h;
        }
        if (pre) sx[j - 128] = xpre;
        __syncthreads();
    }
}
}  // namespace

extern "C" void kernel_launch(void* const* d_in, const int* in_sizes, int n_in,
                              void* d_out, int out_size, void* d_ws, size_t ws_size,
                              hipStream_t stream) {
    const float* noise = (const float*)d_in[0];  // (512,256,100)
    const float* W_ih0 = (const float*)d_in[1];  // (424,100)
    const float* W_hh0 = (const float*)d_in[2];  // (424,106)
    const float* b_ih0 = (const float*)d_in[3];  // (424)
    const float* b_hh0 = (const float*)d_in[4];  // (424)
    const float* W_ih  = (const float*)d_in[5];  // (10,424,106)
    const float* W_hh  = (const float*)d_in[6];  // (10,424,106)
    const float* b_ih  = (const float*)d_in[7];  // (10,424)
    const float* b_hh  = (const float*)d_in[8];  // (10,424)

    float* out = (float*)d_out;                  // (512,256,106) f32
    float* ws  = (float*)d_ws;                   // scratch ping-pong buffer

    dim3 grid(BB), block(448);

    // Layer 0 (input dim 100) -> d_out
    lstm_layer<100><<<grid, block, 0, stream>>>(noise, out, W_ih0, W_hh0, b_ih0, b_hh0);

    // Layers 1..10 (input dim 106), ping-pong ws/out; l=9 (last) lands in out.
    const float* src = out;
    for (int l = 0; l < 10; ++l) {
        float* dst = ((l & 1) == 0) ? ws : out;
        lstm_layer<106><<<grid, block, 0, stream>>>(
            src, dst,
            W_ih + (size_t)l * G4 * H,
            W_hh + (size_t)l * G4 * H,
            b_ih + (size_t)l * G4,
            b_hh + (size_t)l * G4);
        src = dst;
    }
}

// Round 2
// 5818.832 us; speedup vs baseline: 1.2480x; 1.2480x over previous
//
#include <hip/hip_runtime.h>
#include <cmath>

// 11-layer stacked LSTM, S=512, B=256, H=106 (gate dim 424).
// One block per batch row (grid=256 -> 1 block/CU). Thread j owns gate row j.
// R2 changes vs R1:
//  - __launch_bounds__(448, 1): R1's (448,2) capped VGPRs at 128 and spilled
//    ~100 weight values/thread to scratch, reloaded every timestep.
//  - Weights + inputs packed f16, dot via v_dot2_f32_f16 (f32 accumulate):
//    halves VALU ops (216 FMA -> 108 dot2), halves weight VGPRs (216 -> 108),
//    halves LDS read bytes.

namespace {
constexpr int H    = 106;
constexpr int G4   = 424;   // 4*H
constexpr int SEQ  = 512;
constexpr int BB   = 256;

using half2v = __attribute__((ext_vector_type(2))) _Float16;

__device__ __forceinline__ float fdot2(half2v a, half2v b, float acc) {
#if __has_builtin(__builtin_amdgcn_fdot2)
    return __builtin_amdgcn_fdot2(a, b, acc, false);
#else
    return fmaf((float)a[0], (float)b[0], fmaf((float)a[1], (float)b[1], acc));
#endif
}

__device__ __forceinline__ float fast_sigmoid(float x) {
    return 1.0f / (1.0f + __expf(-x));
}
__device__ __forceinline__ float fast_tanh(float x) {
    float t = __expf(2.0f * x);
    return 1.0f - 2.0f / (t + 1.0f);
}

union F4H {
    float4 f4;
    half2v h2[4];
};

// u-vector layout in LDS (f16): [0..107] = x_t (K_IN vals + zero pad),
// [108..213] = h_t, [214..215] = zero pad. 216 f16 = 108 half2 = 27 float4.
template <int K_IN>
__global__ __launch_bounds__(448, 1)
void lstm_layer(const float* __restrict__ x,    // (S, B, K_IN)
                float* __restrict__ y,          // (S, B, H)
                const float* __restrict__ Wih,  // (4H, K_IN)
                const float* __restrict__ Whh,  // (4H, H)
                const float* __restrict__ bih,  // (4H)
                const float* __restrict__ bhh)  // (4H)
{
    const int b = blockIdx.x;    // batch row
    const int j = threadIdx.x;   // gate row (j < 424 active in dot)

    __shared__ __align__(16) _Float16 su[216];
    __shared__ float gates[G4];

    // ---- pack this thread's weight rows into 108 half2 registers ----
    half2v w2[108];
    float bias = 0.0f;
    if (j < G4) {
        const float* wr = Wih + (size_t)j * K_IN;
        #pragma unroll
        for (int k2 = 0; k2 < 54; ++k2) {
            float a = (2 * k2     < K_IN) ? wr[2 * k2]     : 0.0f;
            float c = (2 * k2 + 1 < K_IN) ? wr[2 * k2 + 1] : 0.0f;
            w2[k2] = half2v{(_Float16)a, (_Float16)c};
        }
        const float* hr = Whh + (size_t)j * H;
        #pragma unroll
        for (int k2 = 0; k2 < 53; ++k2) {
            w2[54 + k2] = half2v{(_Float16)hr[2 * k2], (_Float16)hr[2 * k2 + 1]};
        }
        w2[107] = half2v{(_Float16)0.0f, (_Float16)0.0f};
        bias = bih[j] + bhh[j];
    }

    // ---- init state ----
    if (j < 216) su[j] = (_Float16)0.0f;
    __syncthreads();
    if (j < K_IN) su[j] = (_Float16)x[(size_t)b * K_IN + j];   // x_0
    float c = 0.0f;
    const int gate_id = j / H;           // 0:i 1:f 2:g 3:o
    const size_t xstride = (size_t)BB * K_IN;
    const float* xpre_ptr = x + (size_t)BB * K_IN + (size_t)b * K_IN + (j - 128);
    float* yptr = y + (size_t)b * H + j;
    __syncthreads();

    for (int s = 0; s < SEQ; ++s) {
        // prefetch x_{s+1} into registers (latency overlaps the dot phase)
        const bool pre = (s + 1 < SEQ) && (j >= 128) && (j < 128 + K_IN);
        float xpre = 0.0f;
        if (pre) xpre = xpre_ptr[(size_t)s * xstride];

        // ---- phase A: g = bias + W.[x;h], activation ----
        if (j < G4) {
            float a0 = 0.0f, a1 = 0.0f, a2 = 0.0f, a3 = 0.0f;
            #pragma unroll
            for (int q = 0; q < 27; ++q) {
                F4H v;
                v.f4 = *reinterpret_cast<const float4*>(&su[8 * q]);
                a0 = fdot2(w2[4 * q + 0], v.h2[0], a0);
                a1 = fdot2(w2[4 * q + 1], v.h2[1], a1);
                a2 = fdot2(w2[4 * q + 2], v.h2[2], a2);
                a3 = fdot2(w2[4 * q + 3], v.h2[3], a3);
            }
            float g = bias + ((a0 + a1) + (a2 + a3));
            gates[j] = (gate_id == 2) ? fast_tanh(g) : fast_sigmoid(g);
        }
        __syncthreads();

        // ---- phase B: elementwise state update + h broadcast + output ----
        if (j < H) {
            float gi = gates[j];
            float gf = gates[H + j];
            float gg = gates[2 * H + j];
            float go = gates[3 * H + j];
            c = fmaf(gf, c, gi * gg);
            float h = go * fast_tanh(c);
            su[108 + j] = (_Float16)h;
            yptr[(size_t)s * BB * H] = h;
        }
        if (pre) su[j - 128] = (_Float16)xpre;
        __syncthreads();
    }
}
}  // namespace

extern "C" void kernel_launch(void* const* d_in, const int* in_sizes, int n_in,
                              void* d_out, int out_size, void* d_ws, size_t ws_size,
                              hipStream_t stream) {
    const float* noise = (const float*)d_in[0];  // (512,256,100)
    const float* W_ih0 = (const float*)d_in[1];  // (424,100)
    const float* W_hh0 = (const float*)d_in[2];  // (424,106)
    const float* b_ih0 = (const float*)d_in[3];  // (424)
    const float* b_hh0 = (const float*)d_in[4];  // (424)
    const float* W_ih  = (const float*)d_in[5];  // (10,424,106)
    const float* W_hh  = (const float*)d_in[6];  // (10,424,106)
    const float* b_ih  = (const float*)d_in[7];  // (10,424)
    const float* b_hh  = (const float*)d_in[8];  // (10,424)

    float* out = (float*)d_out;                  // (512,256,106) f32
    float* ws  = (float*)d_ws;                   // scratch ping-pong buffer

    dim3 grid(BB), block(448);

    // Layer 0 (input dim 100) -> d_out
    lstm_layer<100><<<grid, block, 0, stream>>>(noise, out, W_ih0, W_hh0, b_ih0, b_hh0);

    // Layers 1..10 (input dim 106), ping-pong ws/out; last lands in out.
    const float* src = out;
    for (int l = 0; l < 10; ++l) {
        float* dst = ((l & 1) == 0) ? ws : out;
        lstm_layer<106><<<grid, block, 0, stream>>>(
            src, dst,
            W_ih + (size_t)l * G4 * H,
            W_hh + (size_t)l * G4 * H,
            b_ih + (size_t)l * G4,
            b_hh + (size_t)l * G4);
        src = dst;
    }
}